// Round 11
// baseline (78.355 us; speedup 1.0000x reference)
//
#include <hip/hip_runtime.h>
#include <hip/hip_bf16.h>
#include <math.h>
#include <stdint.h>
#include <limits.h>

#define BB 8
#define NC 4
#define HH 192
#define WW 192
#define HWP (HH * WW)
#define NPAIR 24            // B * (NC-1)
#define NPD 48              // NPAIR * 2 fields
#define NWRD 576            // HH rows * 3 u64 words per field (= words per image)
#define NCHUNK 8
#define WPC (NWRD / NCHUNK) // 72 words per chunk
#define NBIN 4096           // in-hist d^2 range [0, 4095]; beyond -> overflow list
#define BIGI 1000000000     // matches reference BIG = 1e9 (exact in int32 and f32)

typedef unsigned long long u64;

// ---- kernel 1: argmax + bit-packed fg masks; zero ghist/ovf/out -------------
// wave = 64 consecutive pixels -> __ballot builds one u64 mask word directly.
// grid: 1152 x 256 (= B*HWP threads)
__global__ void k_prep(const float* __restrict__ logits, const int* __restrict__ target,
                       u64* __restrict__ fgbits, unsigned* __restrict__ ghist,
                       int* __restrict__ ovfcnt, int* __restrict__ ovfmax,
                       float* __restrict__ out) {
    int idx = blockIdx.x * 256 + threadIdx.x;
    if (idx < NPD * NBIN) ghist[idx] = 0;
    if (blockIdx.x == 1151) {
        if (threadIdx.x < NPD) ovfcnt[threadIdx.x] = 0;
        else if (threadIdx.x >= 64 && threadIdx.x < 64 + NPD) ovfmax[threadIdx.x - 64] = 0;
        else if (threadIdx.x >= 128 && threadIdx.x < 130) out[threadIdx.x - 128] = 0.0f;
    }
    int b = idx / HWP;
    int p = idx - b * HWP;
    const float* base = logits + (size_t)b * NC * HWP + p;
    float l0 = base[0], l1 = base[HWP], l2 = base[2 * HWP], l3 = base[3 * HWP];
    int pred = 0; float best = l0;
    if (l1 > best) { best = l1; pred = 1; }   // strict > keeps first max (jnp.argmax)
    if (l2 > best) { best = l2; pred = 2; }
    if (l3 > best) { best = l3; pred = 3; }
    int t = target[(size_t)b * HWP + p];
    int lane = threadIdx.x & 63;
    int g = p >> 6;   // word index within field; bit = col&63 (word = i*3 + (j>>6))
#pragma unroll
    for (int cls = 1; cls <= 3; ++cls) {
        u64 mp = __ballot(pred == cls);
        u64 mt = __ballot(t == cls);
        if (lane == 0) {
            int pair = b * 3 + (cls - 1);
            fgbits[(size_t)(pair * 2 + 0) * NWRD + g] = mp;
            fgbits[(size_t)(pair * 2 + 1) * NWRD + g] = mt;
        }
    }
}

// surface word (row i, word k) from fg bitmap F (borders = background)
__device__ __forceinline__ u64 surf_word(const u64* F, int i, int k) {
    u64 r0 = F[i * 3], r1 = F[i * 3 + 1], r2 = F[i * 3 + 2];
    u64 r = F[i * 3 + k];
    u64 u = (i > 0) ? F[(i - 1) * 3 + k] : 0ull;
    u64 d = (i < HH - 1) ? F[(i + 1) * 3 + k] : 0ull;
    u64 lf, rt;
    if (k == 0)      { lf = r0 << 1;                rt = (r0 >> 1) | (r1 << 63); }
    else if (k == 1) { lf = (r1 << 1) | (r0 >> 63); rt = (r1 >> 1) | (r2 << 63); }
    else             { lf = (r2 << 1) | (r1 >> 63); rt = r2 >> 1; }
    return r & ~(u & d & lf & rt);
}

// nearest set-bit horizontal distance to column j in 192-bit row; INT_MAX if empty
__device__ __forceinline__ int rowdist(const u64* w, int j) {
    int qw = j >> 6, qb2 = j & 63;
    int dr = INT_MAX, dl = INT_MAX;
    u64 m = w[qw] & (~0ull << qb2);
    if (m) dr = ((qw << 6) + __ffsll(m) - 1) - j;
    else {
        for (int k = qw + 1; k < 3; ++k)
            if (w[k]) { dr = ((k << 6) + __ffsll(w[k]) - 1) - j; break; }
    }
    u64 ml = w[qw] & (~0ull >> (63 - qb2));
    if (ml) dl = j - ((qw << 6) + 63 - __clzll((long long)ml));
    else {
        for (int k = qw - 1; k >= 0; --k)
            if (w[k]) { dl = j - ((k << 6) + 63 - __clzll((long long)w[k])); break; }
    }
    return min(dl, dr);
}

// ---- kernel 2: surfaces + exact 2D nearest search -> per-pd global hist -----
// Block (chunk, pd): field = surface of pd; queries = surface pixels of pd^1 in
// word slice [chunk*WPC, ...). Empty field -> BIGI exactly (reference BIG path).
// d^2 < 4096 -> LDS hist (merged to ghist); else exact overflow list + max.
// grid: (NCHUNK, NPD), block: 256
__global__ __launch_bounds__(256) void k_query(const u64* __restrict__ fgbits,
                        unsigned* __restrict__ ghist, int* __restrict__ ovfval,
                        int* __restrict__ ovfcnt, int* __restrict__ ovfmax) {
    int chunk = blockIdx.x, pd = blockIdx.y, qpd = pd ^ 1;
    int tid = threadIdx.x;
    __shared__ u64 sF[NWRD];               // fg of pd
    __shared__ u64 sG[NWRD];               // fg of pd^1
    __shared__ u64 sS[NWRD];               // surface of pd (field searched)
    __shared__ uint16_t qb[WPC * 64];      // queries of this chunk (<=4608)
    __shared__ unsigned shist[NBIN];       // 16 KB
    __shared__ int wcnt[WPC + 1];

    for (int t = tid; t < NWRD; t += 256) {
        sF[t] = fgbits[(size_t)pd * NWRD + t];
        sG[t] = fgbits[(size_t)qpd * NWRD + t];
    }
    for (int t = tid; t < NBIN; t += 256) shist[t] = 0;
    __syncthreads();
    for (int w = tid; w < NWRD; w += 256) sS[w] = surf_word(sF, w / 3, w % 3);

    u64 myq = 0;
    if (tid < WPC) {
        int w = chunk * WPC + tid;
        myq = surf_word(sG, w / 3, w % 3);
        wcnt[tid] = __popcll(myq);
    }
    __syncthreads();
    if (tid == 0) {
        int acc = 0;
        for (int w = 0; w < WPC; ++w) { int c = wcnt[w]; wcnt[w] = acc; acc += c; }
        wcnt[WPC] = acc;
    }
    __syncthreads();
    if (tid < WPC) {
        int w = chunk * WPC + tid;
        int i = w / 3, k = w % 3;
        int off = wcnt[tid];
        u64 m = myq;
        while (m) { int bi = __ffsll(m) - 1; m &= m - 1; qb[off++] = (uint16_t)((i << 8) | (k * 64 + bi)); }
    }
    __syncthreads();

    int nq = wcnt[WPC];
    for (int q = tid; q < nq; q += 256) {
        int e = qb[q];
        int qi = e >> 8, qj = e & 255;
        int best = BIGI;
        for (int s = 0; s < HH; ++s) {
            if (s * s >= best) break;                      // exact prune
            int r = qi - s;
            if (r >= 0) {
                int dj = rowdist(sS + r * 3, qj);
                if (dj != INT_MAX) best = min(best, s * s + dj * dj);
            }
            r = qi + s;
            if (s > 0 && r < HH) {
                int dj = rowdist(sS + r * 3, qj);
                if (dj != INT_MAX) best = min(best, s * s + dj * dj);
            }
        }
        if (best < NBIN) {
            atomicAdd(&shist[best], 1u);
        } else {                                           // exact overflow path
            int ix = atomicAdd(&ovfcnt[pd], 1);
            ovfval[(size_t)pd * HWP + ix] = best;
            atomicMax(&ovfmax[pd], best);
        }
    }
    __syncthreads();
    for (int bin = tid; bin < NBIN; bin += 256)
        if (shist[bin]) atomicAdd(&ghist[pd * NBIN + bin], shist[bin]);
}

// ---- kernel 3: per-pair percentile from both dirs' histograms + global mean -
// grid: NPAIR, block: 256 (4 waves). Each thread owns 16 consecutive bins.
// Pair value = max over dirs; mean via atomicAdd(v/24) into out (zeroed by prep).
__global__ __launch_bounds__(256) void k_selfinal(const unsigned* __restrict__ ghist,
                        const int* __restrict__ ovfval, const int* __restrict__ ovfcnt,
                        const int* __restrict__ ovfmax, float* __restrict__ out) {
    int pair = blockIdx.x, tid = threadIdx.x, lane = tid & 63, wid = tid >> 6;
    __shared__ int swt[4];
    __shared__ int sred[4];
    __shared__ int sv95;
    __shared__ float sr[4];   // r100[d], r95[d]

    for (int d = 0; d < 2; ++d) {
        int pd = pair * 2 + d;
        const unsigned* H = ghist + pd * NBIN;

        unsigned c[16];
        int s_t = 0;
#pragma unroll
        for (int u = 0; u < 16; ++u) { c[u] = H[tid * 16 + u]; s_t += (int)c[u]; }

        // block exclusive scan of per-thread sums
        int inc = s_t;
        for (int off = 1; off < 64; off <<= 1) { int t = __shfl_up(inc, off); if (lane >= off) inc += t; }
        if (lane == 63) swt[wid] = inc;
        __syncthreads();
        int woff = 0;
        for (int w = 0; w < wid; ++w) woff += swt[w];
        int total = swt[0] + swt[1] + swt[2] + swt[3];
        int base = woff + inc - s_t;   // exclusive prefix of this thread

        int novf = ovfcnt[pd];
        int n = total + novf;

        // vmax: highest nonzero bin, or overflow max
        int mybin = -1;
#pragma unroll
        for (int u = 0; u < 16; ++u) if (c[u]) mybin = tid * 16 + u;
        for (int off = 32; off; off >>= 1) mybin = max(mybin, __shfl_down(mybin, off));
        if (lane == 0) sred[wid] = mybin;
        __syncthreads();
        int vmax = max(max(sred[0], sred[1]), max(sred[2], sred[3]));
        if (novf > 0) vmax = max(vmax, ovfmax[pd]);
        __syncthreads();

        float r100, r95;
        if (n == 0) {
            r100 = INFINITY; r95 = INFINITY;   // percentile over empty mask -> inf
        } else {
            // replicate jnp: idx = clip(ceil(f32(0.95)*f32(n)) - 1, 0, ...); k = idx+1
            int kk;
            { float kf = ceilf(0.95f * (float)n); kk = (int)kf; if (kk < 1) kk = 1; if (kk > n) kk = n; }
            r100 = sqrtf((float)vmax);
            if (kk <= total) {
                // the unique thread whose bin-chunk spans rank kk scans serially
                if (base < kk && kk <= base + s_t) {
                    int cum = base;
#pragma unroll
                    for (int u = 0; u < 16; ++u) {
                        cum += (int)c[u];
                        if (cum >= kk) { sv95 = tid * 16 + u; break; }
                    }
                }
                __syncthreads();
                r95 = sqrtf((float)sv95);
            } else {
                // rank falls in overflow values (cold path; exact binary search)
                int r = kk - total;
                const int* OV = ovfval + (size_t)pd * HWP;
                int lo = NBIN, hi = vmax;
                while (lo < hi) {
                    int mid = lo + ((hi - lo) >> 1);
                    int cc = 0;
                    for (int k = tid; k < novf; k += 256) if (OV[k] <= mid) cc++;
                    for (int off = 32; off; off >>= 1) cc += __shfl_down(cc, off);
                    if (lane == 0) sred[wid] = cc;
                    __syncthreads();
                    int tot = sred[0] + sred[1] + sred[2] + sred[3];
                    __syncthreads();
                    if (tot >= r) hi = mid; else lo = mid + 1;
                }
                r95 = sqrtf((float)lo);
            }
        }
        if (tid == 0) { sr[d] = r100; sr[2 + d] = r95; }
        __syncthreads();
    }

    if (tid == 0) {
        float v100 = fmaxf(sr[0], sr[1]);
        float v95  = fmaxf(sr[2], sr[3]);
        atomicAdd(&out[0], v100 * (1.0f / NPAIR));
        atomicAdd(&out[1], v95  * (1.0f / NPAIR));
    }
}

extern "C" void kernel_launch(void* const* d_in, const int* in_sizes, int n_in,
                              void* d_out, int out_size, void* d_ws, size_t ws_size,
                              hipStream_t stream) {
    const float* logits = (const float*)d_in[0];
    const int* target = (const int*)d_in[1];
    float* out = (float*)d_out;

    uint8_t* ws = (uint8_t*)d_ws;
    u64*      fgbits = (u64*)ws;                  // 221184 B
    unsigned* ghist  = (unsigned*)(ws + 221184);  // 48*4096*4 = 786432 B
    int*      ovfval = (int*)(ws + 1007616);      // 48*HWP*4 = 7077888 B (cold)
    int*      ovfcnt = (int*)(ws + 8085504);      // 48 ints
    int*      ovfmax = (int*)(ws + 8085696);      // 48 ints
    float*    res    = (float*)(ws + 8085888);    // unused (kept for layout clarity)

    (void)res;
    k_prep<<<(BB * HWP) / 256, 256, 0, stream>>>(logits, target, fgbits, ghist, ovfcnt, ovfmax, out);
    k_query<<<dim3(NCHUNK, NPD), 256, 0, stream>>>(fgbits, ghist, ovfval, ovfcnt, ovfmax);
    k_selfinal<<<NPAIR, 256, 0, stream>>>(ghist, ovfval, ovfcnt, ovfmax, out);
}

// Round 12
// 73.635 us; speedup vs baseline: 1.0641x; 1.0641x over previous
//
#include <hip/hip_runtime.h>
#include <hip/hip_bf16.h>
#include <math.h>
#include <stdint.h>
#include <limits.h>

#define BB 8
#define NC 4
#define HH 192
#define WW 192
#define HWP (HH * WW)
#define NPAIR 24            // B * (NC-1)
#define NPD 48              // NPAIR * 2 fields
#define NWRD 576            // HH rows * 3 u64 words per field (= words per image)
#define NCHUNK 16           // latency-bound: more blocks, less serial work each (R11 lesson)
#define WPC (NWRD / NCHUNK) // 36 words per chunk
#define NBIN 2048           // in-hist d^2 range [0, 2047]; beyond -> exact overflow list
#define BIGI 1000000000     // matches reference BIG = 1e9 (exact in int32 and f32)

typedef unsigned long long u64;

// ---- kernel 1: argmax + bit-packed fg masks; zero ghist/ovf/out -------------
// wave = 64 consecutive pixels -> __ballot builds one u64 mask word directly.
// grid: 1152 x 256 (= B*HWP threads)
__global__ void k_prep(const float* __restrict__ logits, const int* __restrict__ target,
                       u64* __restrict__ fgbits, unsigned* __restrict__ ghist,
                       int* __restrict__ ovfcnt, int* __restrict__ ovfmax,
                       float* __restrict__ out) {
    int idx = blockIdx.x * 256 + threadIdx.x;
    if (idx < NPD * NBIN) ghist[idx] = 0;
    if (blockIdx.x == 1151) {
        if (threadIdx.x < NPD) ovfcnt[threadIdx.x] = 0;
        else if (threadIdx.x >= 64 && threadIdx.x < 64 + NPD) ovfmax[threadIdx.x - 64] = 0;
        else if (threadIdx.x >= 128 && threadIdx.x < 130) out[threadIdx.x - 128] = 0.0f;
    }
    int b = idx / HWP;
    int p = idx - b * HWP;
    const float* base = logits + (size_t)b * NC * HWP + p;
    float l0 = base[0], l1 = base[HWP], l2 = base[2 * HWP], l3 = base[3 * HWP];
    int pred = 0; float best = l0;
    if (l1 > best) { best = l1; pred = 1; }   // strict > keeps first max (jnp.argmax)
    if (l2 > best) { best = l2; pred = 2; }
    if (l3 > best) { best = l3; pred = 3; }
    int t = target[(size_t)b * HWP + p];
    int lane = threadIdx.x & 63;
    int g = p >> 6;   // word index within field; bit = col&63 (word = i*3 + (j>>6))
#pragma unroll
    for (int cls = 1; cls <= 3; ++cls) {
        u64 mp = __ballot(pred == cls);
        u64 mt = __ballot(t == cls);
        if (lane == 0) {
            int pair = b * 3 + (cls - 1);
            fgbits[(size_t)(pair * 2 + 0) * NWRD + g] = mp;
            fgbits[(size_t)(pair * 2 + 1) * NWRD + g] = mt;
        }
    }
}

// surface word (row i, word k) from fg bitmap F (borders = background)
__device__ __forceinline__ u64 surf_word(const u64* F, int i, int k) {
    u64 r0 = F[i * 3], r1 = F[i * 3 + 1], r2 = F[i * 3 + 2];
    u64 r = F[i * 3 + k];
    u64 u = (i > 0) ? F[(i - 1) * 3 + k] : 0ull;
    u64 d = (i < HH - 1) ? F[(i + 1) * 3 + k] : 0ull;
    u64 lf, rt;
    if (k == 0)      { lf = r0 << 1;                rt = (r0 >> 1) | (r1 << 63); }
    else if (k == 1) { lf = (r1 << 1) | (r0 >> 63); rt = (r1 >> 1) | (r2 << 63); }
    else             { lf = (r2 << 1) | (r1 >> 63); rt = r2 >> 1; }
    return r & ~(u & d & lf & rt);
}

// nearest set-bit horizontal distance to column j in 192-bit row; INT_MAX if empty
__device__ __forceinline__ int rowdist(const u64* w, int j) {
    int qw = j >> 6, qb2 = j & 63;
    int dr = INT_MAX, dl = INT_MAX;
    u64 m = w[qw] & (~0ull << qb2);
    if (m) dr = ((qw << 6) + __ffsll(m) - 1) - j;
    else {
        for (int k = qw + 1; k < 3; ++k)
            if (w[k]) { dr = ((k << 6) + __ffsll(w[k]) - 1) - j; break; }
    }
    u64 ml = w[qw] & (~0ull >> (63 - qb2));
    if (ml) dl = j - ((qw << 6) + 63 - __clzll((long long)ml));
    else {
        for (int k = qw - 1; k >= 0; --k)
            if (w[k]) { dl = j - ((k << 6) + 63 - __clzll((long long)w[k])); break; }
    }
    return min(dl, dr);
}

// ---- kernel 2: surfaces + exact 2D nearest search -> per-pd global hist -----
// Block (chunk, pd): field = surface of pd; queries = surface pixels of pd^1 in
// word slice [chunk*WPC, ...). Empty field -> BIGI exactly (reference BIG path).
// d^2 < NBIN -> LDS hist (merged to ghist); else exact overflow list + max.
// grid: (NCHUNK, NPD), block: 256
__global__ __launch_bounds__(256) void k_query(const u64* __restrict__ fgbits,
                        unsigned* __restrict__ ghist, int* __restrict__ ovfval,
                        int* __restrict__ ovfcnt, int* __restrict__ ovfmax) {
    int chunk = blockIdx.x, pd = blockIdx.y, qpd = pd ^ 1;
    int tid = threadIdx.x;
    __shared__ u64 sF[NWRD];               // fg of pd
    __shared__ u64 sG[NWRD];               // fg of pd^1
    __shared__ u64 sS[NWRD];               // surface of pd (field searched)
    __shared__ uint16_t qb[WPC * 64];      // queries of this chunk (<=2304)
    __shared__ unsigned shist[NBIN];       // 8 KB
    __shared__ int wcnt[WPC + 1];

    for (int t = tid; t < NWRD; t += 256) {
        sF[t] = fgbits[(size_t)pd * NWRD + t];
        sG[t] = fgbits[(size_t)qpd * NWRD + t];
    }
    for (int t = tid; t < NBIN; t += 256) shist[t] = 0;
    __syncthreads();
    for (int w = tid; w < NWRD; w += 256) sS[w] = surf_word(sF, w / 3, w % 3);

    u64 myq = 0;
    if (tid < WPC) {
        int w = chunk * WPC + tid;
        myq = surf_word(sG, w / 3, w % 3);
        wcnt[tid] = __popcll(myq);
    }
    __syncthreads();
    if (tid == 0) {
        int acc = 0;
        for (int w = 0; w < WPC; ++w) { int c = wcnt[w]; wcnt[w] = acc; acc += c; }
        wcnt[WPC] = acc;
    }
    __syncthreads();
    if (tid < WPC) {
        int w = chunk * WPC + tid;
        int i = w / 3, k = w % 3;
        int off = wcnt[tid];
        u64 m = myq;
        while (m) { int bi = __ffsll(m) - 1; m &= m - 1; qb[off++] = (uint16_t)((i << 8) | (k * 64 + bi)); }
    }
    __syncthreads();

    int nq = wcnt[WPC];
    for (int q = tid; q < nq; q += 256) {
        int e = qb[q];
        int qi = e >> 8, qj = e & 255;
        int best = BIGI;
        for (int s = 0; s < HH; ++s) {
            if (s * s >= best) break;                      // exact prune
            int r = qi - s;
            if (r >= 0) {
                int dj = rowdist(sS + r * 3, qj);
                if (dj != INT_MAX) best = min(best, s * s + dj * dj);
            }
            r = qi + s;
            if (s > 0 && r < HH) {
                int dj = rowdist(sS + r * 3, qj);
                if (dj != INT_MAX) best = min(best, s * s + dj * dj);
            }
        }
        if (best < NBIN) {
            atomicAdd(&shist[best], 1u);
        } else {                                           // exact overflow path
            int ix = atomicAdd(&ovfcnt[pd], 1);
            ovfval[(size_t)pd * HWP + ix] = best;
            atomicMax(&ovfmax[pd], best);
        }
    }
    __syncthreads();
    for (int bin = tid; bin < NBIN; bin += 256)
        if (shist[bin]) atomicAdd(&ghist[pd * NBIN + bin], shist[bin]);
}

// ---- kernel 3: per-pair percentile from both dirs' histograms + global mean -
// grid: NPAIR, block: 256 (4 waves). Each thread owns 8 consecutive bins.
// Pair value = max over dirs; mean via atomicAdd(v/24) into out (zeroed by prep).
__global__ __launch_bounds__(256) void k_selfinal(const unsigned* __restrict__ ghist,
                        const int* __restrict__ ovfval, const int* __restrict__ ovfcnt,
                        const int* __restrict__ ovfmax, float* __restrict__ out) {
    int pair = blockIdx.x, tid = threadIdx.x, lane = tid & 63, wid = tid >> 6;
    __shared__ int swt[4];
    __shared__ int sred[4];
    __shared__ int sv95;
    __shared__ float sr[4];   // r100[d], r95[d]

    for (int d = 0; d < 2; ++d) {
        int pd = pair * 2 + d;
        const unsigned* H = ghist + pd * NBIN;

        unsigned c[8];
        int s_t = 0;
#pragma unroll
        for (int u = 0; u < 8; ++u) { c[u] = H[tid * 8 + u]; s_t += (int)c[u]; }

        // block exclusive scan of per-thread sums
        int inc = s_t;
        for (int off = 1; off < 64; off <<= 1) { int t = __shfl_up(inc, off); if (lane >= off) inc += t; }
        if (lane == 63) swt[wid] = inc;
        __syncthreads();
        int woff = 0;
        for (int w = 0; w < wid; ++w) woff += swt[w];
        int total = swt[0] + swt[1] + swt[2] + swt[3];
        int base = woff + inc - s_t;   // exclusive prefix of this thread

        int novf = ovfcnt[pd];
        int n = total + novf;

        // vmax: highest nonzero bin, or overflow max
        int mybin = -1;
#pragma unroll
        for (int u = 0; u < 8; ++u) if (c[u]) mybin = tid * 8 + u;
        for (int off = 32; off; off >>= 1) mybin = max(mybin, __shfl_down(mybin, off));
        if (lane == 0) sred[wid] = mybin;
        __syncthreads();
        int vmax = max(max(sred[0], sred[1]), max(sred[2], sred[3]));
        if (novf > 0) vmax = max(vmax, ovfmax[pd]);
        __syncthreads();

        float r100, r95;
        if (n == 0) {
            r100 = INFINITY; r95 = INFINITY;   // percentile over empty mask -> inf
        } else {
            // replicate jnp: idx = clip(ceil(f32(0.95)*f32(n)) - 1, 0, ...); k = idx+1
            int kk;
            { float kf = ceilf(0.95f * (float)n); kk = (int)kf; if (kk < 1) kk = 1; if (kk > n) kk = n; }
            r100 = sqrtf((float)vmax);
            if (kk <= total) {
                // the unique thread whose bin-chunk spans rank kk scans serially
                if (base < kk && kk <= base + s_t) {
                    int cum = base;
#pragma unroll
                    for (int u = 0; u < 8; ++u) {
                        cum += (int)c[u];
                        if (cum >= kk) { sv95 = tid * 8 + u; break; }
                    }
                }
                __syncthreads();
                r95 = sqrtf((float)sv95);
            } else {
                // rank falls in overflow values (cold path; exact binary search)
                int r = kk - total;
                const int* OV = ovfval + (size_t)pd * HWP;
                int lo = NBIN, hi = vmax;
                while (lo < hi) {
                    int mid = lo + ((hi - lo) >> 1);
                    int cc = 0;
                    for (int k = tid; k < novf; k += 256) if (OV[k] <= mid) cc++;
                    for (int off = 32; off; off >>= 1) cc += __shfl_down(cc, off);
                    if (lane == 0) sred[wid] = cc;
                    __syncthreads();
                    int tot = sred[0] + sred[1] + sred[2] + sred[3];
                    __syncthreads();
                    if (tot >= r) hi = mid; else lo = mid + 1;
                }
                r95 = sqrtf((float)lo);
            }
        }
        if (tid == 0) { sr[d] = r100; sr[2 + d] = r95; }
        __syncthreads();
    }

    if (tid == 0) {
        float v100 = fmaxf(sr[0], sr[1]);
        float v95  = fmaxf(sr[2], sr[3]);
        atomicAdd(&out[0], v100 * (1.0f / NPAIR));
        atomicAdd(&out[1], v95  * (1.0f / NPAIR));
    }
}

extern "C" void kernel_launch(void* const* d_in, const int* in_sizes, int n_in,
                              void* d_out, int out_size, void* d_ws, size_t ws_size,
                              hipStream_t stream) {
    const float* logits = (const float*)d_in[0];
    const int* target = (const int*)d_in[1];
    float* out = (float*)d_out;

    uint8_t* ws = (uint8_t*)d_ws;
    u64*      fgbits = (u64*)ws;                  // 221184 B
    unsigned* ghist  = (unsigned*)(ws + 221184);  // 48*2048*4 = 393216 B
    int*      ovfval = (int*)(ws + 614400);       // 48*HWP*4 = 7077888 B (cold)
    int*      ovfcnt = (int*)(ws + 7692288);      // 48 ints
    int*      ovfmax = (int*)(ws + 7692480);      // 48 ints

    k_prep<<<(BB * HWP) / 256, 256, 0, stream>>>(logits, target, fgbits, ghist, ovfcnt, ovfmax, out);
    k_query<<<dim3(NCHUNK, NPD), 256, 0, stream>>>(fgbits, ghist, ovfval, ovfcnt, ovfmax);
    k_selfinal<<<NPAIR, 256, 0, stream>>>(ghist, ovfval, ovfcnt, ovfmax, out);
}